// Round 12
// baseline (319.466 us; speedup 1.0000x reference)
//
#include <hip/hip_runtime.h>
#include <math.h>

// Problem constants (from reference setup_inputs)
constexpr int N    = 50000;   // nodes
constexpr int E    = 800000;  // edges
constexpr int CIN  = 100;     // input channels
constexpr int CH   = 128;     // hidden channels
constexpr int COUT = 47;      // output channels
constexpr int NOUT = 25000;   // original_size (rows emitted)
constexpr int CP   = 48;      // COUT padded (storage stride)
constexpr int NB   = (N + 255) / 256;        // 196 scan blocks
constexpr int PADB = (CH * 128 + 255) / 256; // 64 pad blocks for w2cat
constexpr int TN   = 64;                     // gemm tile nodes (R12: was 128)
constexpr int NT   = (N + TN - 1) / TN;      // 782 gemm blocks (~3.05/CU, 4:3 balance)
constexpr int HS4  = 33;  // hbuf stride in float4 (132 floats, bank-spread 4)
constexpr int FS4  = 9;   // fbuf stride in float4 (36 floats, bank-spread 4)

// ---------------------------------------------------------------------------
// CSR stage 1: in-degree histogram
__global__ void hist_kernel(const int* __restrict__ dst, int* __restrict__ cnt) {
    int i = blockIdx.x * blockDim.x + threadIdx.x;
    if (i < E) atomicAdd(&cnt[dst[i]], 1);
}

// CSR stage 2a: per-block exclusive scan of cnt; extra blocks build the
// concatenated zero-padded layer-2 weights w2cat[k][128] = [w2l|0|w2r|0], b2cat.
__global__ __launch_bounds__(256) void scan_blocks(const int* __restrict__ cnt,
        int* __restrict__ row_ptr, int* __restrict__ blkSum,
        const float* __restrict__ w2l, const float* __restrict__ w2r,
        const float* __restrict__ b2l, float* __restrict__ w2cat,
        float* __restrict__ b2cat) {
    int t = threadIdx.x;
    if (blockIdx.x < NB) {
        __shared__ int s[256];
        int i = blockIdx.x * 256 + t;
        int v = (i < N) ? cnt[i] : 0;
        s[t] = v;
        __syncthreads();
        for (int off = 1; off < 256; off <<= 1) {
            int a = s[t];
            int u = (t >= off) ? s[t - off] : 0;
            __syncthreads();
            s[t] = a + u;
            __syncthreads();
        }
        if (i < N) row_ptr[i] = s[t] - v;
        if (t == 255) blkSum[blockIdx.x] = s[255];
    } else {
        int j = (blockIdx.x - NB) * 256 + t;
        if (j < CH * 128) {
            int k = j >> 7, c = j & 127;
            float v = 0.0f;
            if (c < COUT)                      v = w2l[k * COUT + c];
            else if (c >= 64 && c < 64 + COUT) v = w2r[k * COUT + (c - 64)];
            w2cat[j] = v;
        }
        if (j < 128) b2cat[j] = (j >= 64 && j < 64 + COUT) ? b2l[j - 64] : 0.0f;
    }
}

// CSR stage 2b: each block reduces blkSum[0..bid) itself, applies offset.
__global__ __launch_bounds__(256) void scan_apply(int* __restrict__ row_ptr,
        int* __restrict__ cursor, const int* __restrict__ blkSum) {
    __shared__ int s[256];
    int t = threadIdx.x, bid = blockIdx.x;
    int a = 0;
    for (int j = t; j < bid; j += 256) a += blkSum[j];
    s[t] = a;
    __syncthreads();
    for (int off = 128; off > 0; off >>= 1) {
        if (t < off) s[t] += s[t + off];
        __syncthreads();
    }
    int offset = s[0];
    int i = bid * 256 + t;
    if (i < N) {
        int v = row_ptr[i] + offset;
        row_ptr[i] = v;
        cursor[i]  = v;
        if (i == N - 1) row_ptr[N] = E;
    }
}

// CSR stage 3: bucket-fill edge sources
__global__ void fill_kernel(const int* __restrict__ src, const int* __restrict__ dst,
        int* __restrict__ cursor, int* __restrict__ col) {
    int i = blockIdx.x * blockDim.x + threadIdx.x;
    if (i < E) {
        int d = dst[i];
        int p = atomicAdd(&cursor[d], 1);
        col[p] = src[i];
    }
}

// ---------------------------------------------------------------------------
// gather1 v2: half-wave per node; lane l<25 reads the 400B row as ONE f4 inst.
__global__ __launch_bounds__(256) void gather1_kernel(const float* __restrict__ x,
        const int* __restrict__ row_ptr, const int* __restrict__ col,
        float* __restrict__ agg1) {
    int t = threadIdx.x;
    int n = blockIdx.x * 8 + (t >> 5);
    int l = t & 31;
    int b = row_ptr[n], e = row_ptr[n + 1];
    float inv = 1.0f / (float)max(e - b, 1);
    if (l >= 25) return;
    const float4* xb = (const float4*)x;
    float4 s0 = make_float4(0.f, 0.f, 0.f, 0.f);
    float4 s1 = make_float4(0.f, 0.f, 0.f, 0.f);
    int j = b;
    for (; j + 1 < e; j += 2) {
        float4 v0 = xb[(size_t)col[j]     * 25 + l];
        float4 v1 = xb[(size_t)col[j + 1] * 25 + l];
        s0.x += v0.x; s0.y += v0.y; s0.z += v0.z; s0.w += v0.w;
        s1.x += v1.x; s1.y += v1.y; s1.z += v1.z; s1.w += v1.w;
    }
    if (j < e) {
        float4 v0 = xb[(size_t)col[j] * 25 + l];
        s0.x += v0.x; s0.y += v0.y; s0.z += v0.z; s0.w += v0.w;
    }
    ((float4*)agg1)[(size_t)n * 25 + l] = make_float4(
        (s0.x + s1.x) * inv, (s0.y + s1.y) * inv,
        (s0.z + s1.z) * inv, (s0.w + s1.w) * inv);
}

// ---------------------------------------------------------------------------
// R12 fused gemm v4. R11 post-mortem: 391-block grid on 256 CUs = 2:1 tail
// imbalance + only ~6 waves/CU (occupancy 14%) -> VALU stalled at 37%.
// Now TN=64, 256thr/4 waves; each wave = all 64 nodes x 32 channels, lane
// tile 8x4 (E=0.0176). Grid 782 (~3.05 blk/CU, 4:3 imbalance), LDS 50176B
// -> 3 blocks/CU -> 12 waves/CU (3/SIMD). k-chunks of 32 for both stages.
// Lane map: m_l=lane&7 (node = m_l+8*im), c_l=lane>>3 (ch = wv*32+c_l*4+q).
// fbuf reads: 8-addr broadcast, banks 4*m_l..4*m_l+3 -> conflict-free.
__global__ __launch_bounds__(256) void fused_gemm(
        const float* __restrict__ agg1, const float* __restrict__ x,
        const float* __restrict__ w1l, const float* __restrict__ b1l,
        const float* __restrict__ w1r,
        const float* __restrict__ w2cat, const float* __restrict__ b2cat,
        float* __restrict__ gsrc, float* __restrict__ gself) {
    __shared__ float lds[TN * 132 + 32 * CH];   // 12544 floats = 50176 B
    float4* hbuf4 = (float4*)lds;               // stride HS4=33 f4
    float4* fbuf4 = (float4*)lds;               // stride FS4=9 f4, dead pre-hbuf
    float4* wbuf4 = (float4*)(lds + TN * 132);  // 4096 floats = 1024 f4

    int t = threadIdx.x;
    int base = blockIdx.x * TN;
    int lane = t & 63;
    int wv = __builtin_amdgcn_readfirstlane(t >> 6);  // 0..3
    int m_l = lane & 7;                // node group
    int c_l = lane >> 3;               // 0..7: f4-column within wave's 32-ch slice
    int nmax = N - 1 - base; if (nmax > TN - 1) nmax = TN - 1;

    float a[8][4];
    #pragma unroll
    for (int q = 0; q < 4; ++q) {
        float bv = b1l[wv * 32 + c_l * 4 + q];
        #pragma unroll
        for (int im = 0; im < 8; ++im) a[im][q] = bv;
    }

    // ---- stage 1: h = agg1@w1l + x@w1r + b1l ; k-chunks 32,32,32,4
    for (int ph = 0; ph < 2; ++ph) {
        const float* F = ph ? x : agg1;
        const float* W = ph ? w1r : w1l;
        for (int ci = 0; ci < 4; ++ci) {
            int k0 = ci * 32;
            int kc = (ci == 3) ? 4 : 32;
            int kc4 = kc >> 2;                         // 8 or 1
            for (int i = t; i < TN * kc4; i += 256) {  // feature f4s
                int row = i / kc4, j = i - row * kc4;
                int rr = row <= nmax ? row : nmax;
                fbuf4[row * FS4 + j] =
                    *(const float4*)(F + (size_t)(base + rr) * CIN + k0 + j * 4);
            }
            for (int i = t; i < kc * 32; i += 256) {   // weight f4s [k][128]
                int k = i >> 5, jj = i & 31;
                wbuf4[i] = *(const float4*)(W + (size_t)(k0 + k) * CH + jj * 4);
            }
            __syncthreads();
            for (int kg = 0; kg < kc4; ++kg) {
                float4 f[8];
                #pragma unroll
                for (int im = 0; im < 8; ++im)
                    f[im] = fbuf4[(m_l + 8 * im) * FS4 + kg];
                #pragma unroll
                for (int j = 0; j < 4; ++j) {
                    float4 w0 = wbuf4[(kg * 4 + j) * 32 + wv * 8 + c_l];
                    #pragma unroll
                    for (int im = 0; im < 8; ++im) {
                        float fv = (j == 0) ? f[im].x : (j == 1) ? f[im].y
                                 : (j == 2) ? f[im].z : f[im].w;
                        a[im][0] = fmaf(fv, w0.x, a[im][0]);
                        a[im][1] = fmaf(fv, w0.y, a[im][1]);
                        a[im][2] = fmaf(fv, w0.z, a[im][2]);
                        a[im][3] = fmaf(fv, w0.w, a[im][3]);
                    }
                }
            }
            __syncthreads();
        }
    }
    // spill h tile into hbuf (fbuf alias dead after barrier above)
    #pragma unroll
    for (int im = 0; im < 8; ++im)
        hbuf4[(m_l + 8 * im) * HS4 + wv * 8 + c_l] =
            make_float4(a[im][0], a[im][1], a[im][2], a[im][3]);
    __syncthreads();

    // ---- stage 2: [gsrc 48|pad|gself 48|pad] = h @ w2cat (+b2cat); chunks 32
    #pragma unroll
    for (int q = 0; q < 4; ++q) {
        float bv = b2cat[wv * 32 + c_l * 4 + q];
        #pragma unroll
        for (int im = 0; im < 8; ++im) a[im][q] = bv;
    }
    bool isSelf = (wv >= 2);
    bool skip = isSelf && (base >= NOUT);
    for (int k0 = 0; k0 < CH; k0 += 32) {
        for (int i = t; i < 1024; i += 256)   // 32 k x 32 f4
            wbuf4[i] = *(const float4*)(w2cat + (size_t)(k0 + (i >> 5)) * 128
                                        + (i & 31) * 4);
        __syncthreads();
        if (!skip) {
            for (int kg = 0; kg < 8; ++kg) {
                float4 f[8];
                #pragma unroll
                for (int im = 0; im < 8; ++im)
                    f[im] = hbuf4[(m_l + 8 * im) * HS4 + (k0 >> 2) + kg];
                #pragma unroll
                for (int j = 0; j < 4; ++j) {
                    float4 w0 = wbuf4[(kg * 4 + j) * 32 + wv * 8 + c_l];
                    #pragma unroll
                    for (int im = 0; im < 8; ++im) {
                        float fv = (j == 0) ? f[im].x : (j == 1) ? f[im].y
                                 : (j == 2) ? f[im].z : f[im].w;
                        a[im][0] = fmaf(fv, w0.x, a[im][0]);
                        a[im][1] = fmaf(fv, w0.y, a[im][1]);
                        a[im][2] = fmaf(fv, w0.z, a[im][2]);
                        a[im][3] = fmaf(fv, w0.w, a[im][3]);
                    }
                }
            }
        }
        __syncthreads();
    }
    // store real channels: global col = (wv&1)*32 + c_l*4, valid < 48
    if (!skip) {
        int colr = (wv & 1) * 32 + c_l * 4;
        if (colr < CP) {
            float* G = isSelf ? gself : gsrc;
            int lim = isSelf ? NOUT : N;
            #pragma unroll
            for (int im = 0; im < 8; ++im) {
                int n = base + m_l + 8 * im;
                if (n < lim)
                    *(float4*)(G + (size_t)n * CP + colr) =
                        make_float4(a[im][0], a[im][1], a[im][2], a[im][3]);
            }
        }
    }
}

// ---------------------------------------------------------------------------
// final: out[n] = log_softmax( mean_{s in N(n)} gsrc[s] + gself[n] )
__global__ __launch_bounds__(64) void final_kernel(const float* __restrict__ gsrc,
        const float* __restrict__ gself, const int* __restrict__ row_ptr,
        const int* __restrict__ col, float* __restrict__ out) {
    int n = blockIdx.x;
    int c = threadIdx.x;
    int b = row_ptr[n], e = row_ptr[n + 1];
    float inv = 1.0f / (float)max(e - b, 1);
    float a0 = 0.f, a1 = 0.f;
    if (c < CP) {
        int j = b;
        for (; j + 1 < e; j += 2) {
            a0 += gsrc[(size_t)col[j] * CP + c];
            a1 += gsrc[(size_t)col[j + 1] * CP + c];
        }
        if (j < e) a0 += gsrc[(size_t)col[j] * CP + c];
    }
    float val = (c < COUT) ? ((a0 + a1) * inv + gself[(size_t)n * CP + c]) : -INFINITY;
    float m = val;
    #pragma unroll
    for (int off = 32; off > 0; off >>= 1) m = fmaxf(m, __shfl_xor(m, off, 64));
    float ex = (c < COUT) ? expf(val - m) : 0.f;
    float ssum = ex;
    #pragma unroll
    for (int off = 32; off > 0; off >>= 1) ssum += __shfl_xor(ssum, off, 64);
    if (c < COUT) out[(size_t)n * COUT + c] = val - m - logf(ssum);
}

// ---------------------------------------------------------------------------
extern "C" void kernel_launch(void* const* d_in, const int* in_sizes, int n_in,
                              void* d_out, int out_size, void* d_ws, size_t ws_size,
                              hipStream_t stream) {
    const float* x   = (const float*)d_in[0];
    const int*   ei  = (const int*)d_in[1];   // [2, E]: row 0 = src, row 1 = dst
    const int*   src = ei;
    const int*   dst = ei + E;
    const float* w1l = (const float*)d_in[3];
    const float* b1l = (const float*)d_in[4];
    const float* w1r = (const float*)d_in[5];
    const float* w2l = (const float*)d_in[6];
    const float* b2l = (const float*)d_in[7];
    const float* w2r = (const float*)d_in[8];
    float* out = (float*)d_out;

    // ws: ints [cnt N | row_ptr N+1 | cursor N | blkSum NB | col E]
    // floats [agg1 N*CIN | gsrc N*CP | gself NOUT*CP | w2cat CH*128 | b2cat 128]
    int* cnt     = (int*)d_ws;
    int* row_ptr = cnt + N;
    int* cursor  = row_ptr + N + 1;
    int* blkSum  = cursor + N;
    int* col     = blkSum + NB;
    size_t intWords = (size_t)N + (N + 1) + N + NB + E;
    intWords = (intWords + 3) & ~(size_t)3;
    float* agg1  = (float*)d_ws + intWords;
    float* gsrc  = agg1 + (size_t)N * CIN;
    float* gself = gsrc + (size_t)N * CP;
    float* w2cat = gself + (size_t)NOUT * CP;
    float* b2cat = w2cat + (size_t)CH * 128;
    // total ws ~38.4 MB (< 58.6 MB proven available)

    hipMemsetAsync(cnt, 0, (size_t)N * sizeof(int), stream);
    hist_kernel <<<(E + 255) / 256, 256, 0, stream>>>(dst, cnt);
    scan_blocks <<<NB + PADB, 256, 0, stream>>>(cnt, row_ptr, blkSum,
                                                w2l, w2r, b2l, w2cat, b2cat);
    scan_apply  <<<NB, 256, 0, stream>>>(row_ptr, cursor, blkSum);
    fill_kernel <<<(E + 255) / 256, 256, 0, stream>>>(src, dst, cursor, col);
    gather1_kernel<<<N / 8, 256, 0, stream>>>(x, row_ptr, col, agg1);
    fused_gemm  <<<NT, 256, 0, stream>>>(agg1, x, w1l, b1l, w1r,
                                         w2cat, b2cat, gsrc, gself);
    final_kernel<<<NOUT, 64, 0, stream>>>(gsrc, gself, row_ptr, col, out);
}